// Round 11
// baseline (226.738 us; speedup 1.0000x reference)
//
#include <hip/hip_runtime.h>
#include <hip/hip_bf16.h>

#define HH 192
#define WW 192
#define HWPROD (192*192)
#define EPSBN 1e-5f

typedef _Float16 f16x8 __attribute__((ext_vector_type(8)));
typedef _Float16 f16x4 __attribute__((ext_vector_type(4)));
typedef _Float16 f16x2 __attribute__((ext_vector_type(2)));
typedef float f32x4 __attribute__((ext_vector_type(4)));

// ---------------------------------------------------------------------------
// prep: fold BN into conv weights/biases; build MFMA-fragment-major f16 copy
// of the final projection weight (mapping proven R2-R10, c-major K):
//   whF[((nt*32+kg)*64 + lane)*8 + j] = lw[n][k]*bnscale(n),
//   n = nt*16 + (lane&15), k = kg*32 + ((lane>>4)&3)*8 + j
// ---------------------------------------------------------------------------
__global__ void prep_k(const float* __restrict__ w0, const float* __restrict__ b0,
                       const float* __restrict__ g0, const float* __restrict__ beta0,
                       const float* __restrict__ m0, const float* __restrict__ v0,
                       const float* __restrict__ wnw0, const float* __restrict__ wnb0,
                       const float* __restrict__ wng0, const float* __restrict__ wnbe0,
                       const float* __restrict__ wnm0, const float* __restrict__ wnv0,
                       const float* __restrict__ wnw1, const float* __restrict__ wnb1,
                       const float* __restrict__ wng1, const float* __restrict__ wnbe1,
                       const float* __restrict__ wnm1, const float* __restrict__ wnv1,
                       const float* __restrict__ wnw2, const float* __restrict__ wnb2,
                       const float* __restrict__ wng2, const float* __restrict__ wnbe2,
                       const float* __restrict__ wnm2, const float* __restrict__ wnv2,
                       const float* __restrict__ lw, const float* __restrict__ lb,
                       const float* __restrict__ lg, const float* __restrict__ lbeta,
                       const float* __restrict__ lm, const float* __restrict__ lv,
                       _Float16* __restrict__ whF,
                       float* __restrict__ lbf,
                       float* __restrict__ w0f, float* __restrict__ b0f,
                       float* __restrict__ wnP)
{
    int idx = blockIdx.x * 256 + threadIdx.x;
    if (idx < 65536) {
        int j    = idx & 7;
        int lane = (idx >> 3) & 63;
        int kg   = (idx >> 9) & 31;
        int nt   = idx >> 14;
        int k = kg * 32 + ((lane >> 4) & 3) * 8 + j;
        int n = nt * 16 + (lane & 15);
        float s = lg[n] * rsqrtf(lv[n] + EPSBN);
        whF[idx] = (_Float16)(lw[n * 1024 + k] * s);
    } else if (idx < 65600) {
        int j = idx - 65536;
        float s = lg[j] * rsqrtf(lv[j] + EPSBN);
        lbf[j] = (lb[j] - lm[j]) * s + lbeta[j];
    } else if (idx < 66624) {
        int t = idx - 65600;
        int o = t >> 4;
        float s = g0[o] * rsqrtf(v0[o] + EPSBN);
        w0f[t] = w0[t] * s;
    } else if (idx < 66688) {
        int o = idx - 66624;
        float s = g0[o] * rsqrtf(v0[o] + EPSBN);
        b0f[o] = (b0[o] - m0[o]) * s + beta0[o];
    } else if (idx < 66936) {
        int t = idx - 66688;
        // wnP layout: [0,24) w0n  [24,32) b0n  [32,96) w1n  [96,104) b1n
        //             [104,232) w2n  [232,248) b2n   (all BN-fused)
        if (t < 24)       { int o = t / 3;           float s = wng0[o] * rsqrtf(wnv0[o] + EPSBN); wnP[t] = wnw0[t] * s; }
        else if (t < 32)  { int o = t - 24;          float s = wng0[o] * rsqrtf(wnv0[o] + EPSBN); wnP[t] = (wnb0[o] - wnm0[o]) * s + wnbe0[o]; }
        else if (t < 96)  { int t2 = t - 32;  int o = t2 >> 3; float s = wng1[o] * rsqrtf(wnv1[o] + EPSBN); wnP[t] = wnw1[t2] * s; }
        else if (t < 104) { int o = t - 96;          float s = wng1[o] * rsqrtf(wnv1[o] + EPSBN); wnP[t] = (wnb1[o] - wnm1[o]) * s + wnbe1[o]; }
        else if (t < 232) { int t2 = t - 104; int o = t2 >> 3; float s = wng2[o] * rsqrtf(wnv2[o] + EPSBN); wnP[t] = wnw2[t2] * s; }
        else              { int o = t - 232;         float s = wng2[o] * rsqrtf(wnv2[o] + EPSBN); wnP[t] = (wnb2[o] - wnm2[o]) * s + wnbe2[o]; }
    }
}

// ---------------------------------------------------------------------------
// main fused kernel: R10 structure with conv0 FUSED (x1 halo computed
// in-block from x; no x1L round trip, no conv0 launch). Main is HBM-write
// bound (out = 576 MiB f32 ~ 96 us floor); the added conv VALU hides under
// that envelope.
//  phase0a: stage x f32 halo (16ch x 198px) -> xS; wSt/bS -> LDS; WeightNet
//           -> gzF.            (S0)
//  phase0b: conv 16->64 + BN + ReLU from xS/wSt, f16 pairs -> xtP. (S1)
//  then identical to R10: gq->regs (S2), 8 K-chunks double-buffered A,
//  MFMA per wave (nt, mt2), epilogue via Cb.
//  LDS 62,848 B -> 2 blocks/CU = 16 waves/CU.
// ---------------------------------------------------------------------------
__global__ __launch_bounds__(512, 4) void pconv_main_k(const float* __restrict__ gxyz,
                                                       const float* __restrict__ x,
                                                       const _Float16* __restrict__ whF,
                                                       const float* __restrict__ lbf,
                                                       const float* __restrict__ wnP,
                                                       const float* __restrict__ w0f,
                                                       const float* __restrict__ b0f,
                                                       float* __restrict__ out)
{
    __shared__ __align__(16) char smem[62848];
    f16x2*    xtP = reinterpret_cast<f16x2*>(smem);              // [32][201] dwords = 25728 B
    _Float16* A0  = reinterpret_cast<_Float16*>(smem + 25728);   // 16 rows x 64 units = 16384 B
    _Float16* A1  = reinterpret_cast<_Float16*>(smem + 42112);   // 16384 B
    _Float16* gzF = reinterpret_cast<_Float16*>(smem + 25728);   // [64][152]=19456 B, spans A0/A1 head (dead after S2)
    float*    xS  = reinterpret_cast<float*>(smem + 45184);      // [16][198] f32 = 12672 B, aliases A1 tail (dead after S1)
    float*    wSt = reinterpret_cast<float*>(smem + 58496);      // [16][64] f32 = 4096 B (dead after S1)
    float*    bS  = reinterpret_cast<float*>(smem + 62592);      // 64 f32 (dead after S1)
    float*    Cb  = reinterpret_cast<float*>(smem);              // [64][67] fp32, aliases xtP (epilogue only)

    const int tid = threadIdx.x;
    const int bid = blockIdx.x;
    const int b   = bid / (HH * 3);
    const int rem = bid % (HH * 3);
    const int h   = rem / 3;
    const int wc0 = (rem % 3) * 64;

    // --- phase 0a: weights, x f32 halo, WeightNet ---
    for (int t = tid; t < 1024; t += 512)
        wSt[(t & 15) * 64 + (t >> 4)] = w0f[t];     // wSt[ci][co]
    if (tid < 64) bS[tid] = b0f[tid];

    // stage x halo (16 ch x 198 halo px), zero OOB; coalesced 66-f32 runs
    for (int i = tid; i < 3168; i += 512) {
        int ci   = i / 198;
        int colr = i - ci * 198;
        int col  = colr % 66;
        int r    = colr / 66;
        int hr = h + r - 1;
        int wc = wc0 + col - 1;
        float v = 0.f;
        if (hr >= 0 && hr < HH && wc >= 0 && wc < WW)
            v = x[((size_t)(b * 16 + ci) * HH + hr) * WW + wc];
        xS[ci * 198 + colr] = v;
    }

    // WeightNet 3->8->8->16 (BN+ReLU fused): 576 (pixel,tap) units -> gzF
    for (int u = tid; u < 576; u += 512) {
        int pixu = u & 63, tap = u >> 6;
        size_t base = ((size_t)(b * 3) * 9 + tap) * HWPROD + (size_t)h * WW + wc0 + pixu;
        float z0 = gxyz[base];
        float z1 = gxyz[base + (size_t)9 * HWPROD];
        float z2 = gxyz[base + (size_t)18 * HWPROD];
        float h0[8], h1[8];
#pragma unroll
        for (int o = 0; o < 8; o++) {
            float a = wnP[24 + o] + wnP[o * 3 + 0] * z0 + wnP[o * 3 + 1] * z1 + wnP[o * 3 + 2] * z2;
            h0[o] = fmaxf(a, 0.f);
        }
#pragma unroll
        for (int o = 0; o < 8; o++) {
            float a = wnP[96 + o];
#pragma unroll
            for (int c = 0; c < 8; c++) a += wnP[32 + o * 8 + c] * h0[c];
            h1[o] = fmaxf(a, 0.f);
        }
        float g[16];
#pragma unroll
        for (int o = 0; o < 16; o++) {
            float a = wnP[232 + o];
#pragma unroll
            for (int c = 0; c < 8; c++) a += wnP[104 + o * 8 + c] * h1[c];
            g[o] = fmaxf(a, 0.f);
        }
        f16x8 lo, hi;
#pragma unroll
        for (int o = 0; o < 8; o++) { lo[o] = (_Float16)g[o]; hi[o] = (_Float16)g[o + 8]; }
        *(f16x8*)&gzF[pixu * 152 + tap * 16]     = lo;
        *(f16x8*)&gzF[pixu * 152 + tap * 16 + 8] = hi;
    }
    __syncthreads();   // S0: xS + wSt + bS + gzF visible

    // --- phase 0b: fused conv0: x1 halo = relu(bn(conv1x1)) -> xtP pairs ---
    for (int q = tid; q < 1584; q += 512) {
        int c8   = q & 7;
        int colr = q >> 3;          // 0..197 = r*66 + col
        int col  = colr % 66;
        int r    = colr / 66;
        int hr = h + r - 1;
        int wc = wc0 + col - 1;
        f16x2 p0 = f16x2{0, 0}, p1 = f16x2{0, 0}, p2 = f16x2{0, 0}, p3 = f16x2{0, 0};
        if (hr >= 0 && hr < HH && wc >= 0 && wc < WW) {
            f32x4 acc0 = *(const f32x4*)&bS[c8 * 8];
            f32x4 acc1 = *(const f32x4*)&bS[c8 * 8 + 4];
#pragma unroll
            for (int ci = 0; ci < 16; ci++) {
                float xv = xS[ci * 198 + colr];
                f32x4 xb = {xv, xv, xv, xv};
                f32x4 w0v = *(const f32x4*)&wSt[ci * 64 + c8 * 8];
                f32x4 w1v = *(const f32x4*)&wSt[ci * 64 + c8 * 8 + 4];
                acc0 = __builtin_elementwise_fma(xb, w0v, acc0);
                acc1 = __builtin_elementwise_fma(xb, w1v, acc1);
            }
            p0 = f16x2{(_Float16)fmaxf(acc0[0], 0.f), (_Float16)fmaxf(acc0[1], 0.f)};
            p1 = f16x2{(_Float16)fmaxf(acc0[2], 0.f), (_Float16)fmaxf(acc0[3], 0.f)};
            p2 = f16x2{(_Float16)fmaxf(acc1[0], 0.f), (_Float16)fmaxf(acc1[1], 0.f)};
            p3 = f16x2{(_Float16)fmaxf(acc1[2], 0.f), (_Float16)fmaxf(acc1[3], 0.f)};
        }
        xtP[(c8 * 4 + 0) * 201 + colr] = p0;
        xtP[(c8 * 4 + 1) * 201 + colr] = p1;
        xtP[(c8 * 4 + 2) * 201 + colr] = p2;
        xtP[(c8 * 4 + 3) * 201 + colr] = p3;
    }
    __syncthreads();   // S1: xtP ready (xS/wSt/bS now dead)

    // phase-1 roles: thread = (pix, oh, cp): 2 channels {2cp,2cp+1} x 8 o's
    const int pix = tid & 63;
    const int u8  = tid >> 6;            // 0..7
    const int oh  = u8 & 1;              // o-half: o in [oh*8, oh*8+8)
    const int cp  = u8 >> 1;             // c-pair within the chunk's 8 channels
    // phase-2 roles: wave = (nt, mt2)
    const int lane = tid & 63;
    const int wv   = tid >> 6;
    const int nt   = wv & 3;
    const int mt2  = wv >> 2;

    // gz 8 o's x 9 taps -> registers as f16x2 pairs (no converts)
    f16x2 gq2[9][4];
#pragma unroll
    for (int t = 0; t < 9; t++) {
        union { f16x8 v; f16x2 h[4]; } G;
        G.v = *(const f16x8*)&gzF[pix * 152 + t * 16 + oh * 8];
#pragma unroll
        for (int d = 0; d < 4; d++) gq2[t][d] = G.h[d];
    }
    __syncthreads();   // S2: gzF consumed; A0/A1 region may now be overwritten

    const int mt = pix >> 4;             // m-tile of this pixel

    // phase 1: A-chunk (channels 8cc..8cc+8), all-f16, b128 fragment writes
    auto phase1 = [&](int cc, _Float16* Ab) {
        union { f16x2 h2[4]; f16x8 v; } av0, av1;
#pragma unroll
        for (int d = 0; d < 4; d++) { av0.h2[d] = f16x2{0, 0}; av1.h2[d] = f16x2{0, 0}; }
        const f16x2* xrow = xtP + (cc * 4 + cp) * 201 + pix;
#pragma unroll
        for (int ky = 0; ky < 3; ky++) {
#pragma unroll
            for (int kx = 0; kx < 3; kx++) {
                const int t = ky * 3 + kx;
                f16x2 xq = xrow[ky * 66 + kx];
                f16x2 xb0 = __builtin_shufflevector(xq, xq, 0, 0);
                f16x2 xb1 = __builtin_shufflevector(xq, xq, 1, 1);
#pragma unroll
                for (int d = 0; d < 4; d++) {
                    av0.h2[d] = __builtin_elementwise_fma(xb0, gq2[t][d], av0.h2[d]);
                    av1.h2[d] = __builtin_elementwise_fma(xb1, gq2[t][d], av1.h2[d]);
                }
            }
        }
        // fragment rows (16B units): row = cp*4 + mt; lane = p15 + 16*q
        const int row = cp * 4 + mt;
        *(f16x8*)&Ab[(row * 64 + (pix & 15) + 16 * oh) * 8]       = av0.v;
        *(f16x8*)&Ab[(row * 64 + (pix & 15) + 16 * (2 + oh)) * 8] = av1.v;
    };

    const f16x8* whF8 = (const f16x8*)whF;
    f32x4 facc[2];
    facc[0] = f32x4{0.f, 0.f, 0.f, 0.f};
    facc[1] = f32x4{0.f, 0.f, 0.f, 0.f};

    phase1(0, A0);
    __syncthreads();   // S3: A(0) ready

#pragma unroll 2
    for (int cc = 0; cc < 8; cc++) {
        const _Float16* Ac = (cc & 1) ? A1 : A0;
#pragma unroll
        for (int kb = 0; kb < 4; kb++) {
            const int kg = cc * 4 + kb;
            f16x8 a0 = *(const f16x8*)&Ac[((kb * 4 + 2 * mt2) * 64 + lane) * 8];
            f16x8 a1 = *(const f16x8*)&Ac[((kb * 4 + 2 * mt2 + 1) * 64 + lane) * 8];
            f16x8 wh = whF8[((nt * 32 + kg) << 6) + lane];
            facc[0] = __builtin_amdgcn_mfma_f32_16x16x32_f16(a0, wh, facc[0], 0, 0, 0);
            facc[1] = __builtin_amdgcn_mfma_f32_16x16x32_f16(a1, wh, facc[1], 0, 0, 0);
        }
        if (cc < 7) phase1(cc + 1, (cc & 1) ? A0 : A1);
        __syncthreads();   // A(cc+1) ready; also fences buffer reuse / epilogue
    }

    // epilogue: C/D layout col=lane&15 (=n within tile), row=(lane>>4)*4+reg
    // Cb stride 67 -> conflict-light. Aliases xtP (reads done before last barrier).
    {
        const int n = nt * 16 + (lane & 15);
        const float bias = lbf[n];
#pragma unroll
        for (int m = 0; m < 2; m++) {
            const int pixm = (2 * mt2 + m) * 16 + (lane >> 4) * 4;
#pragma unroll
            for (int r = 0; r < 4; r++)
                Cb[n * 67 + pixm + r] = fmaxf(facc[m][r] + bias, 0.f);
        }
    }
    __syncthreads();
    {
        const int pixq = tid & 63, jq = tid >> 6;   // 8 j-groups x 8 rows
        size_t ob = ((size_t)b * 64 + jq * 8) * HWPROD + (size_t)h * WW + wc0 + pixq;
#pragma unroll
        for (int i = 0; i < 8; i++) {
            out[ob + (size_t)i * HWPROD] = Cb[(jq * 8 + i) * 67 + pixq];
        }
    }
}

// ---------------------------------------------------------------------------
extern "C" void kernel_launch(void* const* d_in, const int* in_sizes, int n_in,
                              void* d_out, int out_size, void* d_ws, size_t ws_size,
                              hipStream_t stream) {
    const float* x    = (const float*)d_in[0];
    // d_in[1] = group_mask: unused by the reference
    const float* gxyz = (const float*)d_in[2];

    char* ws = (char*)d_ws;
    _Float16* whF = (_Float16*)ws;                        // 65,536 halves
    float* lbf = (float*)(whF + 65536);                   // 64
    float* w0f = lbf + 64;                                // 1024
    float* b0f = w0f + 1024;                              // 64
    float* wnP = b0f + 64;                                // 248

    prep_k<<<262, 256, 0, stream>>>(
        (const float*)d_in[3],  (const float*)d_in[4],  (const float*)d_in[5],
        (const float*)d_in[6],  (const float*)d_in[7],  (const float*)d_in[8],
        (const float*)d_in[9],  (const float*)d_in[10], (const float*)d_in[11],
        (const float*)d_in[12], (const float*)d_in[13], (const float*)d_in[14],
        (const float*)d_in[15], (const float*)d_in[16], (const float*)d_in[17],
        (const float*)d_in[18], (const float*)d_in[19], (const float*)d_in[20],
        (const float*)d_in[21], (const float*)d_in[22], (const float*)d_in[23],
        (const float*)d_in[24], (const float*)d_in[25], (const float*)d_in[26],
        (const float*)d_in[27], (const float*)d_in[28], (const float*)d_in[29],
        (const float*)d_in[30], (const float*)d_in[31], (const float*)d_in[32],
        whF, lbf, w0f, b0f, wnP);

    pconv_main_k<<<4 * HH * 3, 512, 0, stream>>>(gxyz, x, whF, lbf, wnP,
                                                 w0f, b0f, (float*)d_out);
}

// Round 12
// 218.230 us; speedup vs baseline: 1.0390x; 1.0390x over previous
//
#include <hip/hip_runtime.h>
#include <hip/hip_bf16.h>

#define HH 192
#define WW 192
#define HWPROD (192*192)
#define EPSBN 1e-5f

typedef _Float16 f16x8 __attribute__((ext_vector_type(8)));
typedef _Float16 f16x4 __attribute__((ext_vector_type(4)));
typedef _Float16 f16x2 __attribute__((ext_vector_type(2)));
typedef float f32x4 __attribute__((ext_vector_type(4)));

// ---------------------------------------------------------------------------
// prep_conv0: ONE launch doing both independent jobs.
//  blocks [0,576):   conv0 -- x[B,16,H,W] -> x1 = relu(bn(conv1x1)) f16
//                    pixel-major [B,H,W,64]; BN fold done locally in LDS
//                    (no dependency on the prep blocks).
//  blocks [576,838): prep -- BN-fold + fragment-major f16 projection weight
//                    (mapping proven R2-R10, c-major K):
//    whF[((nt*32+kg)*64 + lane)*8 + j] = lw[n][k]*bnscale(n),
//    n = nt*16 + (lane&15), k = kg*32 + ((lane>>4)&3)*8 + j
//  plus lbf (folded bias) and wnP (folded WeightNet params).
// ---------------------------------------------------------------------------
__global__ __launch_bounds__(256) void prep_conv0_k(
                       const float* __restrict__ w0, const float* __restrict__ b0,
                       const float* __restrict__ g0, const float* __restrict__ beta0,
                       const float* __restrict__ m0, const float* __restrict__ v0,
                       const float* __restrict__ wnw0, const float* __restrict__ wnb0,
                       const float* __restrict__ wng0, const float* __restrict__ wnbe0,
                       const float* __restrict__ wnm0, const float* __restrict__ wnv0,
                       const float* __restrict__ wnw1, const float* __restrict__ wnb1,
                       const float* __restrict__ wng1, const float* __restrict__ wnbe1,
                       const float* __restrict__ wnm1, const float* __restrict__ wnv1,
                       const float* __restrict__ wnw2, const float* __restrict__ wnb2,
                       const float* __restrict__ wng2, const float* __restrict__ wnbe2,
                       const float* __restrict__ wnm2, const float* __restrict__ wnv2,
                       const float* __restrict__ lw, const float* __restrict__ lb,
                       const float* __restrict__ lg, const float* __restrict__ lbeta,
                       const float* __restrict__ lm, const float* __restrict__ lv,
                       const float* __restrict__ x,
                       _Float16* __restrict__ x1L,
                       _Float16* __restrict__ whF,
                       float* __restrict__ lbf,
                       float* __restrict__ wnP)
{
    const int tid = threadIdx.x;

    if (blockIdx.x >= 576) {
        // ---------------- prep blocks ----------------
        int idx = (blockIdx.x - 576) * 256 + tid;
        if (idx < 65536) {
            int j    = idx & 7;
            int lane = (idx >> 3) & 63;
            int kg   = (idx >> 9) & 31;
            int nt   = idx >> 14;
            int k = kg * 32 + ((lane >> 4) & 3) * 8 + j;
            int n = nt * 16 + (lane & 15);
            float s = lg[n] * rsqrtf(lv[n] + EPSBN);
            whF[idx] = (_Float16)(lw[n * 1024 + k] * s);
        } else if (idx < 65600) {
            int j = idx - 65536;
            float s = lg[j] * rsqrtf(lv[j] + EPSBN);
            lbf[j] = (lb[j] - lm[j]) * s + lbeta[j];
        } else if (idx < 65848) {
            int t = idx - 65600;
            // wnP layout: [0,24) w0n  [24,32) b0n  [32,96) w1n  [96,104) b1n
            //             [104,232) w2n  [232,248) b2n   (all BN-fused)
            if (t < 24)       { int o = t / 3;           float s = wng0[o] * rsqrtf(wnv0[o] + EPSBN); wnP[t] = wnw0[t] * s; }
            else if (t < 32)  { int o = t - 24;          float s = wng0[o] * rsqrtf(wnv0[o] + EPSBN); wnP[t] = (wnb0[o] - wnm0[o]) * s + wnbe0[o]; }
            else if (t < 96)  { int t2 = t - 32;  int o = t2 >> 3; float s = wng1[o] * rsqrtf(wnv1[o] + EPSBN); wnP[t] = wnw1[t2] * s; }
            else if (t < 104) { int o = t - 96;          float s = wng1[o] * rsqrtf(wnv1[o] + EPSBN); wnP[t] = (wnb1[o] - wnm1[o]) * s + wnbe1[o]; }
            else if (t < 232) { int t2 = t - 104; int o = t2 >> 3; float s = wng2[o] * rsqrtf(wnv2[o] + EPSBN); wnP[t] = wnw2[t2] * s; }
            else if (t < 248) { int o = t - 232;         float s = wng2[o] * rsqrtf(wnv2[o] + EPSBN); wnP[t] = (wnb2[o] - wnm2[o]) * s + wnbe2[o]; }
        }
        return;
    }

    // ---------------- conv0 blocks ----------------
    __shared__ float wSt[16][64];   // [cin][cout], BN-folded locally
    __shared__ float bS[64];
    for (int t = tid; t < 1024; t += 256) {
        int o = t >> 4, ci = t & 15;
        float s = g0[o] * rsqrtf(v0[o] + EPSBN);
        wSt[ci][o] = w0[t] * s;
    }
    if (tid < 64) {
        float s = g0[tid] * rsqrtf(v0[tid] + EPSBN);
        bS[tid] = (b0[tid] - m0[tid]) * s + beta0[tid];
    }
    __syncthreads();

    const int pix = blockIdx.x * 256 + tid;   // conv0 grid covers exactly B*H*W
    const int b = pix / HWPROD;
    const int p = pix - b * HWPROD;

    float xv[16];
#pragma unroll
    for (int cin = 0; cin < 16; cin++)
        xv[cin] = x[((size_t)b * 16 + cin) * HWPROD + p];

    _Float16* outp = x1L + (size_t)pix * 64;
#pragma unroll
    for (int co = 0; co < 64; co += 4) {
        f32x4 a = { bS[co], bS[co + 1], bS[co + 2], bS[co + 3] };
#pragma unroll
        for (int cin = 0; cin < 16; cin++) {
            float xc = xv[cin];
            a.x += wSt[cin][co + 0] * xc;
            a.y += wSt[cin][co + 1] * xc;
            a.z += wSt[cin][co + 2] * xc;
            a.w += wSt[cin][co + 3] * xc;
        }
        a.x = fmaxf(a.x, 0.f); a.y = fmaxf(a.y, 0.f);
        a.z = fmaxf(a.z, 0.f); a.w = fmaxf(a.w, 0.f);
        *(f16x4*)(outp + co) = __builtin_convertvector(a, f16x4);
    }
}

// ---------------------------------------------------------------------------
// main fused kernel: R10 proven structure (92 us, at the HBM-write envelope).
//   xtP[pairRow = c/2][col] f16x2, row stride 201 dwords (201 % 32 = 9):
//     phase-1 reads dword-stride-1 (conflict-free), staging writes spread.
//   A buffers: exact 64-unit (16B) rows; phase-2 b128 reads unit-stride
//   (conflict-free); phase-1 b128 fragment writes quarter-wave stride-1.
//  One block = 64-pixel row segment (M=64), 512 thr = 8 waves.
//  LDS 58,496 B -> 2 blocks/CU = 16 waves/CU.
// ---------------------------------------------------------------------------
__global__ __launch_bounds__(512, 4) void pconv_main_k(const float* __restrict__ gxyz,
                                                       const _Float16* __restrict__ x1L,
                                                       const _Float16* __restrict__ whF,
                                                       const float* __restrict__ lbf,
                                                       const float* __restrict__ wnP,
                                                       float* __restrict__ out)
{
    __shared__ __align__(16) char smem[58496];
    f16x2*    xtP = reinterpret_cast<f16x2*>(smem);              // [32][201] dwords = 25728 B
    _Float16* A0  = reinterpret_cast<_Float16*>(smem + 25728);   // 16 rows x 64 units = 16384 B
    _Float16* A1  = reinterpret_cast<_Float16*>(smem + 42112);   // 16384 B
    _Float16* gzF = reinterpret_cast<_Float16*>(smem + 25728);   // [64][152]=19456 B, spans A0/A1 (dead after S2)
    float*    Cb  = reinterpret_cast<float*>(smem);              // [64][67] fp32, aliases xtP

    const int tid = threadIdx.x;
    const int bid = blockIdx.x;
    const int b   = bid / (HH * 3);
    const int rem = bid % (HH * 3);
    const int h   = rem / 3;
    const int wc0 = (rem % 3) * 64;

    // stage f16 x1 halo into pair-major layout: rows h-1..h+1, cols wc0-1..
    // wc0+64, 64 ch; zero OOB. Load octet (b128 global), scatter 4 b32 LDS.
    for (int q = tid; q < 1584; q += 512) {
        int c8   = q & 7;
        int colr = q >> 3;          // 0..197 = r*66 + col
        int col  = colr % 66;
        int r    = colr / 66;
        int hr = h + r - 1;
        int wc = wc0 + col - 1;
        union { f16x8 v; f16x2 p[4]; } U;
        U.v = f16x8{};
        if (hr >= 0 && hr < HH && wc >= 0 && wc < WW) {
            U.v = *(const f16x8*)(x1L + (((size_t)b * HH + hr) * WW + wc) * 64 + c8 * 8);
        }
#pragma unroll
        for (int i = 0; i < 4; i++)
            xtP[(c8 * 4 + i) * 201 + colr] = U.p[i];
    }

    // WeightNet 3->8->8->16 (BN+ReLU fused): 576 (pixel,tap) units.
    for (int u = tid; u < 576; u += 512) {
        int pixu = u & 63, tap = u >> 6;
        size_t base = ((size_t)(b * 3) * 9 + tap) * HWPROD + (size_t)h * WW + wc0 + pixu;
        float z0 = gxyz[base];
        float z1 = gxyz[base + (size_t)9 * HWPROD];
        float z2 = gxyz[base + (size_t)18 * HWPROD];
        float h0[8], h1[8];
#pragma unroll
        for (int o = 0; o < 8; o++) {
            float a = wnP[24 + o] + wnP[o * 3 + 0] * z0 + wnP[o * 3 + 1] * z1 + wnP[o * 3 + 2] * z2;
            h0[o] = fmaxf(a, 0.f);
        }
#pragma unroll
        for (int o = 0; o < 8; o++) {
            float a = wnP[96 + o];
#pragma unroll
            for (int c = 0; c < 8; c++) a += wnP[32 + o * 8 + c] * h0[c];
            h1[o] = fmaxf(a, 0.f);
        }
        float g[16];
#pragma unroll
        for (int o = 0; o < 16; o++) {
            float a = wnP[232 + o];
#pragma unroll
            for (int c = 0; c < 8; c++) a += wnP[104 + o * 8 + c] * h1[c];
            g[o] = fmaxf(a, 0.f);
        }
        f16x8 lo, hi;
#pragma unroll
        for (int o = 0; o < 8; o++) { lo[o] = (_Float16)g[o]; hi[o] = (_Float16)g[o + 8]; }
        *(f16x8*)&gzF[pixu * 152 + tap * 16]     = lo;
        *(f16x8*)&gzF[pixu * 152 + tap * 16 + 8] = hi;
    }
    __syncthreads();   // S1: xtP + gzF visible

    // phase-1 roles: thread = (pix, oh, cp): 2 channels {2cp,2cp+1} x 8 o's
    const int pix = tid & 63;
    const int u8  = tid >> 6;            // 0..7
    const int oh  = u8 & 1;              // o-half: o in [oh*8, oh*8+8)
    const int cp  = u8 >> 1;             // c-pair within the chunk's 8 channels
    // phase-2 roles: wave = (nt, mt2)
    const int lane = tid & 63;
    const int wv   = tid >> 6;
    const int nt   = wv & 3;
    const int mt2  = wv >> 2;

    // gz 8 o's x 9 taps -> registers as f16x2 pairs (no converts)
    f16x2 gq2[9][4];
#pragma unroll
    for (int t = 0; t < 9; t++) {
        union { f16x8 v; f16x2 h[4]; } G;
        G.v = *(const f16x8*)&gzF[pix * 152 + t * 16 + oh * 8];
#pragma unroll
        for (int d = 0; d < 4; d++) gq2[t][d] = G.h[d];
    }
    __syncthreads();   // S2: gzF consumed; A0/A1 region may now be overwritten

    const int mt = pix >> 4;             // m-tile of this pixel

    // phase 1: A-chunk (channels 8cc..8cc+8), all-f16, b128 fragment writes
    auto phase1 = [&](int cc, _Float16* Ab) {
        union { f16x2 h2[4]; f16x8 v; } av0, av1;
#pragma unroll
        for (int d = 0; d < 4; d++) { av0.h2[d] = f16x2{0, 0}; av1.h2[d] = f16x2{0, 0}; }
        const f16x2* xrow = xtP + (cc * 4 + cp) * 201 + pix;
#pragma unroll
        for (int ky = 0; ky < 3; ky++) {
#pragma unroll
            for (int kx = 0; kx < 3; kx++) {
                const int t = ky * 3 + kx;
                f16x2 xq = xrow[ky * 66 + kx];
                f16x2 xb0 = __builtin_shufflevector(xq, xq, 0, 0);
                f16x2 xb1 = __builtin_shufflevector(xq, xq, 1, 1);
#pragma unroll
                for (int d = 0; d < 4; d++) {
                    av0.h2[d] = __builtin_elementwise_fma(xb0, gq2[t][d], av0.h2[d]);
                    av1.h2[d] = __builtin_elementwise_fma(xb1, gq2[t][d], av1.h2[d]);
                }
            }
        }
        // fragment rows (16B units): row = cp*4 + mt; lane = p15 + 16*q
        const int row = cp * 4 + mt;
        *(f16x8*)&Ab[(row * 64 + (pix & 15) + 16 * oh) * 8]       = av0.v;
        *(f16x8*)&Ab[(row * 64 + (pix & 15) + 16 * (2 + oh)) * 8] = av1.v;
    };

    const f16x8* whF8 = (const f16x8*)whF;
    f32x4 facc[2];
    facc[0] = f32x4{0.f, 0.f, 0.f, 0.f};
    facc[1] = f32x4{0.f, 0.f, 0.f, 0.f};

    phase1(0, A0);
    __syncthreads();   // S3: A(0) ready

#pragma unroll 2
    for (int cc = 0; cc < 8; cc++) {
        const _Float16* Ac = (cc & 1) ? A1 : A0;
#pragma unroll
        for (int kb = 0; kb < 4; kb++) {
            const int kg = cc * 4 + kb;
            f16x8 a0 = *(const f16x8*)&Ac[((kb * 4 + 2 * mt2) * 64 + lane) * 8];
            f16x8 a1 = *(const f16x8*)&Ac[((kb * 4 + 2 * mt2 + 1) * 64 + lane) * 8];
            f16x8 wh = whF8[((nt * 32 + kg) << 6) + lane];
            facc[0] = __builtin_amdgcn_mfma_f32_16x16x32_f16(a0, wh, facc[0], 0, 0, 0);
            facc[1] = __builtin_amdgcn_mfma_f32_16x16x32_f16(a1, wh, facc[1], 0, 0, 0);
        }
        if (cc < 7) phase1(cc + 1, (cc & 1) ? A0 : A1);
        __syncthreads();   // A(cc+1) ready; also fences buffer reuse / epilogue
    }

    // epilogue: C/D layout col=lane&15 (=n within tile), row=(lane>>4)*4+reg
    // Cb stride 67 -> conflict-light. Aliases xtP (reads done before last barrier).
    {
        const int n = nt * 16 + (lane & 15);
        const float bias = lbf[n];
#pragma unroll
        for (int m = 0; m < 2; m++) {
            const int pixm = (2 * mt2 + m) * 16 + (lane >> 4) * 4;
#pragma unroll
            for (int r = 0; r < 4; r++)
                Cb[n * 67 + pixm + r] = fmaxf(facc[m][r] + bias, 0.f);
        }
    }
    __syncthreads();
    {
        const int pixq = tid & 63, jq = tid >> 6;   // 8 j-groups x 8 rows
        size_t ob = ((size_t)b * 64 + jq * 8) * HWPROD + (size_t)h * WW + wc0 + pixq;
#pragma unroll
        for (int i = 0; i < 8; i++) {
            out[ob + (size_t)i * HWPROD] = Cb[(jq * 8 + i) * 67 + pixq];
        }
    }
}

// ---------------------------------------------------------------------------
extern "C" void kernel_launch(void* const* d_in, const int* in_sizes, int n_in,
                              void* d_out, int out_size, void* d_ws, size_t ws_size,
                              hipStream_t stream) {
    const float* x    = (const float*)d_in[0];
    // d_in[1] = group_mask: unused by the reference
    const float* gxyz = (const float*)d_in[2];

    char* ws = (char*)d_ws;
    _Float16* x1L = (_Float16*)ws;                        // 9,437,184 halves (18.9 MB)
    _Float16* whF = x1L + 9437184;                        // 65,536 halves
    float* lbf = (float*)(whF + 65536);                   // 64
    float* wnP = lbf + 64;                                // 248

    prep_conv0_k<<<838, 256, 0, stream>>>(
        (const float*)d_in[3],  (const float*)d_in[4],  (const float*)d_in[5],
        (const float*)d_in[6],  (const float*)d_in[7],  (const float*)d_in[8],
        (const float*)d_in[9],  (const float*)d_in[10], (const float*)d_in[11],
        (const float*)d_in[12], (const float*)d_in[13], (const float*)d_in[14],
        (const float*)d_in[15], (const float*)d_in[16], (const float*)d_in[17],
        (const float*)d_in[18], (const float*)d_in[19], (const float*)d_in[20],
        (const float*)d_in[21], (const float*)d_in[22], (const float*)d_in[23],
        (const float*)d_in[24], (const float*)d_in[25], (const float*)d_in[26],
        (const float*)d_in[27], (const float*)d_in[28], (const float*)d_in[29],
        (const float*)d_in[30], (const float*)d_in[31], (const float*)d_in[32],
        x, x1L, whF, lbf, wnP);

    pconv_main_k<<<4 * HH * 3, 512, 0, stream>>>(gxyz, x1L, whF, lbf, wnP,
                                                 (float*)d_out);
}